// Round 3
// baseline (253.447 us; speedup 1.0000x reference)
//
#include <hip/hip_runtime.h>

#define BH (512*2048)
#define BHA 1048576ull                   // 512*2048 elems (one activation plane)
#define PPLANE (512ull*8192ull)          // elems per partial plane [512][8192]
#define PLANE_BYTES (PPLANE*2ull)        // bf16
#define AB_ELEMS (2ull*512*2048)         // bf16 activations (inputs + prevstate)

typedef __attribute__((ext_vector_type(8))) short short8;
typedef __attribute__((ext_vector_type(4))) float floatx4;
typedef __attribute__((ext_vector_type(4))) unsigned int uint4v;
typedef __attribute__((ext_vector_type(8))) unsigned short ushort8v;

// pack two f32 -> two bf16 (round-half-up) in one dword (verified R2-R4)
__device__ inline unsigned pk2(float a, float b){
    unsigned ua = __builtin_bit_cast(unsigned, a) + 0x8000u;
    unsigned ub = __builtin_bit_cast(unsigned, b) + 0x8000u;
    return __builtin_amdgcn_perm(ub, ua, 0x07060302u);
}
__device__ inline unsigned short f2bf1(float x){
    return (unsigned short)((__builtin_bit_cast(unsigned, x) + 0x8000u) >> 16);
}
__device__ inline float bf2f(unsigned short s){
    return __builtin_bit_cast(float, ((unsigned)s) << 16);
}
__device__ inline int swz(int r, int g){ return r*4 + (g ^ ((r>>1)&3)); }
__device__ inline float fsig(float x){ return __builtin_amdgcn_rcpf(1.f + __expf(-x)); }
__device__ inline float ftanh(float x){ return 2.f*fsig(2.f*x) - 1.f; }

// ---------------------------------------------------------------------------
// Activation cast only. Casts inputs (plane 0) and states[0] (plane 1) to
// bf16 flat. 1024 blocks.
// ---------------------------------------------------------------------------
__global__ __launch_bounds__(256) void prep_act(
    const float* __restrict__ inputs, const float* __restrict__ states,
    unsigned short* __restrict__ Ab)
{
    const size_t off = ((size_t)blockIdx.x * 256 + threadIdx.x) * 8;
    const float* src = (off < BHA) ? (inputs + off) : (states + (off - BHA));
    floatx4 v0 = *(const floatx4*)src;
    floatx4 v1 = *(const floatx4*)(src + 4);
    uint4v w;
    w.x = pk2(v0[0],v0[1]); w.y = pk2(v0[2],v0[3]);
    w.z = pk2(v1[0],v1[1]); w.w = pk2(v1[2],v1[3]);
    *(uint4v*)(Ab + off) = w;
}

// ---------------------------------------------------------------------------
// Fused GEMM R3: fully register-staged (no global_load_lds -> no vmcnt(0)
// drain at barriers), 2-deep pipeline on the B (fp32 weight) path.
// Block 128x128, 4 waves of 64x64 (4x4 x mfma_16x16x32_bf16), BK=32,
// grid (64 n-panels, 4 m-blocks, 4 K-chunks).
// Iter kk: issue B loads for tile kk+2 (reg set kk&1), issue A loads for
// tile kk+1, ds_read frags + 16 MFMA on tile kk, then ds_write tile kk+1
// (A regs + B reg set (kk+1)&1, loaded a full iteration ago), barrier.
// LDS layout: [row][granule ^ ((row>>1)&3)] XOR swizzle (verified R2,
// SQ_LDS_BANK_CONFLICT = 0).
// ---------------------------------------------------------------------------
__global__ __launch_bounds__(256, 3) void gemm_fused(
    const float* __restrict__ Wi, const float* __restrict__ Ui,
    const float* __restrict__ Wf, const float* __restrict__ Uf,
    const float* __restrict__ Wg, const float* __restrict__ Ug,
    const float* __restrict__ Wc, const float* __restrict__ Uc,
    const unsigned short* __restrict__ Ab, unsigned short* __restrict__ P)
{
    __shared__ unsigned short As[2][4096];   // [m 0..127][k-granule swizzled]
    __shared__ unsigned short Bs[2][4096];   // [n 0..127][k-granule swizzled]

    const int t = threadIdx.x, lane = t & 63, wave = t >> 6;
    const int nblk = blockIdx.x, gate = nblk >> 4, nb = nblk & 15;
    const int m0 = blockIdx.y * 128, z = blockIdx.z;

    // ---- B (weight) staging setup ----
    const float* Bsel;
    if (z < 2) { switch (gate){ case 0: Bsel=Wi; break; case 1: Bsel=Wf; break;
                                case 2: Bsel=Wg; break; default: Bsel=Wc; } }
    else       { switch (gate){ case 0: Bsel=Ui; break; case 1: Bsel=Uf; break;
                                case 2: Bsel=Ug; break; default: Bsel=Uc; } }
    const int n   = t & 127;             // owned B column within panel
    const int o0  = t >> 7;              // first k-octet (0/1); second = o0+2
    const int swkB = (n >> 1) & 3;       // granule swizzle key for row n
    const float* Bp0 = Bsel + ((size_t)((z & 1) * 1024 + o0 * 8)) * 2048
                            + nb * 128 + n;
    const float* Bp1 = Bp0 + (size_t)16 * 2048;   // octet o0+2
    // B LDS write offsets (shorts): phys granule = octet ^ swkB
    const int wb0 = n * 32 + (((o0    ) ^ swkB) << 3);
    const int wb1 = n * 32 + (((o0 + 2) ^ swkB) << 3);

    // ---- A staging setup (register-staged from bf16 Ab) ----
    // thread t: row r = t>>1 (0..127), half h = t&1 -> granules 2h, 2h+1
    const int ar = t >> 1, ah = t & 1;
    const int swkA = (ar >> 1) & 3;
    const unsigned short* Aptr = Ab + (size_t)(z >> 1) * BHA
                               + (size_t)(m0 + ar) * 2048 + (z & 1) * 1024
                               + ah * 16;
    const int wa0 = ar * 32 + (((2*ah    ) ^ swkA) << 3);
    const int wa1 = ar * 32 + (((2*ah + 1) ^ swkA) << 3);

    floatx4 acc[4][4];
    #pragma unroll
    for (int i = 0; i < 4; i++)
        #pragma unroll
        for (int j = 0; j < 4; j++)
            acc[i][j] = (floatx4){0.f,0.f,0.f,0.f};

    const int wm = (wave & 1) * 64, wn = (wave >> 1) * 64;
    const int row16 = lane & 15, g4 = lane >> 4;
    const int fgx = ((g4 ^ ((row16 >> 1) & 3)) << 3);  // swizzled frag granule

    float uB0a[8], uB0b[8], uB1a[8], uB1b[8];
    uint4v uA0, uA1;

#define B_LOAD(d0, d1, tile) do { \
    const float* q0_ = Bp0 + (size_t)(tile) * 65536; \
    const float* q1_ = Bp1 + (size_t)(tile) * 65536; \
    _Pragma("unroll") for (int j = 0; j < 8; j++) d0[j] = q0_[(size_t)j * 2048]; \
    _Pragma("unroll") for (int j = 0; j < 8; j++) d1[j] = q1_[(size_t)j * 2048]; \
} while(0)

#define B_WRITE(buf, s0, s1) do { \
    *(uint4v*)&Bs[buf][wb0] = (uint4v){pk2(s0[0],s0[1]), pk2(s0[2],s0[3]), \
                                       pk2(s0[4],s0[5]), pk2(s0[6],s0[7])}; \
    *(uint4v*)&Bs[buf][wb1] = (uint4v){pk2(s1[0],s1[1]), pk2(s1[2],s1[3]), \
                                       pk2(s1[4],s1[5]), pk2(s1[6],s1[7])}; \
} while(0)

#define A_LOAD(tile) do { \
    const unsigned short* ap_ = Aptr + (size_t)(tile) * 32; \
    uA0 = *(const uint4v*)ap_; uA1 = *(const uint4v*)(ap_ + 8); \
} while(0)

#define A_WRITE(buf) do { \
    *(uint4v*)&As[buf][wa0] = uA0; *(uint4v*)&As[buf][wa1] = uA1; \
} while(0)

#define FRAGS_MFMA(buf) do { \
    short8 afr[4], bfr[4]; \
    _Pragma("unroll") for (int mi = 0; mi < 4; mi++) \
        afr[mi] = *(const short8*)&As[buf][(wm + mi*16 + row16)*32 + fgx]; \
    _Pragma("unroll") for (int ni = 0; ni < 4; ni++) \
        bfr[ni] = *(const short8*)&Bs[buf][(wn + ni*16 + row16)*32 + fgx]; \
    _Pragma("unroll") for (int mi = 0; mi < 4; mi++) \
        _Pragma("unroll") for (int ni = 0; ni < 4; ni++) \
            acc[mi][ni] = __builtin_amdgcn_mfma_f32_16x16x32_bf16( \
                afr[mi], bfr[ni], acc[mi][ni], 0, 0, 0); \
} while(0)

    // ---- prologue: tiles 0 (write now) and 1 (write at iter 0) ----
    B_LOAD(uB0a, uB0b, 0);
    B_LOAD(uB1a, uB1b, 1);
    A_LOAD(0);
    A_WRITE(0);
    B_WRITE(0, uB0a, uB0b);
    __syncthreads();

    for (int kk = 0; kk < 32; kk += 2) {
        // ---- even iter kk: compute buf0; load tile kk+2 -> uB0; write kk+1
        if (kk < 30) { B_LOAD(uB0a, uB0b, kk + 2); }
        A_LOAD(kk + 1);
        FRAGS_MFMA(0);
        A_WRITE(1);
        B_WRITE(1, uB1a, uB1b);
        __syncthreads();
        // ---- odd iter kk+1: compute buf1; load tile kk+3 -> uB1; write kk+2
        if (kk < 30) {
            B_LOAD(uB1a, uB1b, kk + 3);
            A_LOAD(kk + 2);
        }
        FRAGS_MFMA(1);
        if (kk < 30) {
            A_WRITE(0);
            B_WRITE(0, uB0a, uB0b);
        }
        __syncthreads();
    }

#undef B_LOAD
#undef B_WRITE
#undef A_LOAD
#undef A_WRITE
#undef FRAGS_MFMA

    unsigned short* dst = P + (size_t)z * PPLANE;
    const int gbase = gate * 2048 + nb * 128;
    #pragma unroll
    for (int mi = 0; mi < 4; mi++)
        #pragma unroll
        for (int ni = 0; ni < 4; ni++)
            #pragma unroll
            for (int j = 0; j < 4; j++) {
                int row = m0 + wm + mi*16 + g4*4 + j;
                int col = gbase + wn + ni*16 + row16;
                dst[(size_t)row * 8192 + col] = f2bf1(acc[mi][ni][j]);
            }
}

// ---------------------------------------------------------------------------
// Fallback GEMM (fused fp32 staging) for small ws_size.
// ---------------------------------------------------------------------------
__global__ __launch_bounds__(256, 2) void gemm_tile(
    const float* __restrict__ inputs, const float* __restrict__ states,
    const float* __restrict__ Wi, const float* __restrict__ Ui,
    const float* __restrict__ Wf, const float* __restrict__ Uf,
    const float* __restrict__ Wg, const float* __restrict__ Ug,
    const float* __restrict__ Wc, const float* __restrict__ Uc,
    unsigned short* __restrict__ P, int KB)
{
    __shared__ uint4v As[2][512];
    __shared__ uint4v Bs[2][512];

    const int t = threadIdx.x;
    const int m0 = blockIdx.y * 128;
    const int z = blockIdx.z;
    const int nblk = blockIdx.x;
    const int gate = nblk >> 4;
    const int c0 = (nblk & 15) * 128;
    const int gk = z * KB;

    const float* Abase; const float* Bsel; int ko;
    if (gk < 2048) {
        Abase = inputs; ko = gk;
        switch (gate){ case 0: Bsel=Wi; break; case 1: Bsel=Wf; break;
                       case 2: Bsel=Wg; break; default: Bsel=Wc; }
    } else {
        Abase = states; ko = gk - 2048;
        switch (gate){ case 0: Bsel=Ui; break; case 1: Bsel=Uf; break;
                       case 2: Bsel=Ug; break; default: Bsel=Uc; }
    }
    const int NIT = KB >> 5;

    const int lane = t & 63, wave = t >> 6;
    const int wm = (wave & 1) * 64, wn = (wave >> 1) * 64;
    const int row16 = lane & 15, g4 = lane >> 4;
    const int ar = t >> 2, ag = t & 3;
    const int bn = t & 127, bg2 = (t >> 7) * 2;

    const float* Ap = Abase + (size_t)(m0 + ar) * 2048 + ko + ag * 8;
    const float* Bp = Bsel + (size_t)ko * 2048 + c0 + bn;

    floatx4 acc[4][4];
    #pragma unroll
    for (int i = 0; i < 4; i++)
        #pragma unroll
        for (int j = 0; j < 4; j++)
            acc[i][j] = (floatx4){0.f,0.f,0.f,0.f};

    floatx4 a0,a1,a2,a3; float b0[8], b1[8];
    a0 = *(const floatx4*)Ap;             a1 = *(const floatx4*)(Ap + 4);
    a2 = *(const floatx4*)(Ap + 64*2048); a3 = *(const floatx4*)(Ap + 64*2048 + 4);
    #pragma unroll
    for (int j = 0; j < 8; j++) b0[j] = Bp[(size_t)(bg2*8 + j) * 2048];
    #pragma unroll
    for (int j = 0; j < 8; j++) b1[j] = Bp[(size_t)(bg2*8 + 8 + j) * 2048];
    {
        uint4v w;
        w.x=pk2(a0[0],a0[1]); w.y=pk2(a0[2],a0[3]); w.z=pk2(a1[0],a1[1]); w.w=pk2(a1[2],a1[3]);
        As[0][swz(ar, ag)] = w;
        w.x=pk2(a2[0],a2[1]); w.y=pk2(a2[2],a2[3]); w.z=pk2(a3[0],a3[1]); w.w=pk2(a3[2],a3[3]);
        As[0][swz(ar+64, ag)] = w;
        w.x=pk2(b0[0],b0[1]); w.y=pk2(b0[2],b0[3]); w.z=pk2(b0[4],b0[5]); w.w=pk2(b0[6],b0[7]);
        Bs[0][swz(bn, bg2)] = w;
        w.x=pk2(b1[0],b1[1]); w.y=pk2(b1[2],b1[3]); w.z=pk2(b1[4],b1[5]); w.w=pk2(b1[6],b1[7]);
        Bs[0][swz(bn, bg2+1)] = w;
    }

    for (int kk = 0; kk < NIT; kk++) {
        __syncthreads();
        const int cur = kk & 1;
        if (kk + 1 < NIT) {
            const float* ap = Ap + (kk+1) * 32;
            a0 = *(const floatx4*)ap;             a1 = *(const floatx4*)(ap + 4);
            a2 = *(const floatx4*)(ap + 64*2048); a3 = *(const floatx4*)(ap + 64*2048 + 4);
            const float* bp = Bp + (size_t)(kk+1) * 32 * 2048;
            #pragma unroll
            for (int j = 0; j < 8; j++) b0[j] = bp[(size_t)(bg2*8 + j) * 2048];
            #pragma unroll
            for (int j = 0; j < 8; j++) b1[j] = bp[(size_t)(bg2*8 + 8 + j) * 2048];
        }
        short8 afr[4], bfr[4];
        #pragma unroll
        for (int mi = 0; mi < 4; mi++)
            afr[mi] = *(const short8*)&As[cur][swz(wm + mi*16 + row16, g4)];
        #pragma unroll
        for (int ni = 0; ni < 4; ni++)
            bfr[ni] = *(const short8*)&Bs[cur][swz(wn + ni*16 + row16, g4)];
        #pragma unroll
        for (int mi = 0; mi < 4; mi++)
            #pragma unroll
            for (int ni = 0; ni < 4; ni++)
                acc[mi][ni] = __builtin_amdgcn_mfma_f32_16x16x32_bf16(
                    afr[mi], bfr[ni], acc[mi][ni], 0, 0, 0);
        if (kk + 1 < NIT) {
            const int nxt = cur ^ 1;
            uint4v w;
            w.x=pk2(a0[0],a0[1]); w.y=pk2(a0[2],a0[3]); w.z=pk2(a1[0],a1[1]); w.w=pk2(a1[2],a1[3]);
            As[nxt][swz(ar, ag)] = w;
            w.x=pk2(a2[0],a2[1]); w.y=pk2(a2[2],a2[3]); w.z=pk2(a3[0],a3[1]); w.w=pk2(a3[2],a3[3]);
            As[nxt][swz(ar+64, ag)] = w;
            w.x=pk2(b0[0],b0[1]); w.y=pk2(b0[2],b0[3]); w.z=pk2(b0[4],b0[5]); w.w=pk2(b0[6],b0[7]);
            Bs[nxt][swz(bn, bg2)] = w;
            w.x=pk2(b1[0],b1[1]); w.y=pk2(b1[2],b1[3]); w.z=pk2(b1[4],b1[5]); w.w=pk2(b1[6],b1[7]);
            Bs[nxt][swz(bn, bg2+1)] = w;
        }
    }

    unsigned short* dst = P + (size_t)z * PPLANE;
    const int gbase = gate * 2048 + c0;
    #pragma unroll
    for (int mi = 0; mi < 4; mi++)
        #pragma unroll
        for (int ni = 0; ni < 4; ni++)
            #pragma unroll
            for (int j = 0; j < 4; j++) {
                int row = m0 + wm + mi*16 + g4*4 + j;
                int col = gbase + wn + ni*16 + row16;
                dst[(size_t)row * 8192 + col] = f2bf1(acc[mi][ni][j]);
            }
}

// activations + LSTM combine
__global__ __launch_bounds__(256) void combine_kernel(
    float* __restrict__ out, const unsigned short* __restrict__ P,
    const float* __restrict__ states,
    const float* __restrict__ bi, const float* __restrict__ bfv,
    const float* __restrict__ bg, const float* __restrict__ bc, int nz)
{
    const int idx = (blockIdx.x * 256 + threadIdx.x) * 8;
    const int row = idx >> 11;
    const int h = idx & 2047;
    const size_t base = (size_t)row * 8192 + h;

    float xi[8], xf[8], xg[8], xc[8];
    #pragma unroll
    for (int e = 0; e < 8; e++) {
        xi[e] = bi[h+e]; xf[e] = bfv[h+e]; xg[e] = bg[h+e]; xc[e] = bc[h+e];
    }
    for (int z = 0; z < nz; z++) {
        const unsigned short* Pz = P + (size_t)z * PPLANE;
        ushort8v vi = *(const ushort8v*)&Pz[base];
        ushort8v vf = *(const ushort8v*)&Pz[base + 2048];
        ushort8v vg = *(const ushort8v*)&Pz[base + 4096];
        ushort8v vc = *(const ushort8v*)&Pz[base + 6144];
        #pragma unroll
        for (int e = 0; e < 8; e++) {
            xi[e] += bf2f(vi[e]); xf[e] += bf2f(vf[e]);
            xg[e] += bf2f(vg[e]); xc[e] += bf2f(vc[e]);
        }
    }

    const float* po = states + BH;
    floatx4 pov[2];
    pov[0] = *(const floatx4*)&po[idx];
    pov[1] = *(const floatx4*)&po[idx + 4];

    floatx4 vcv[2], vsv[2];
    #pragma unroll
    for (int q = 0; q < 2; q++)
        #pragma unroll
        for (int j = 0; j < 4; j++) {
            int e = q*4 + j;
            float c = fsig(xf[e]) * pov[q][j] + fsig(xi[e]) * ftanh(xc[e]);
            vcv[q][j] = c;
            vsv[q][j] = fsig(xg[e]) * ftanh(c);
        }
    #pragma unroll
    for (int q = 0; q < 2; q++) {
        *(floatx4*)&out[idx + q*4]        = vcv[q];
        *(floatx4*)&out[BH + idx + q*4]   = vsv[q];
        *(floatx4*)&out[2*BH + idx + q*4] = vcv[q];
    }
}

extern "C" void kernel_launch(void* const* d_in, const int* in_sizes, int n_in,
                              void* d_out, int out_size, void* d_ws, size_t ws_size,
                              hipStream_t stream) {
    const float* inputs = (const float*)d_in[0];
    const float* states = (const float*)d_in[1];
    const float* Wi = (const float*)d_in[2];
    const float* Ui = (const float*)d_in[3];
    const float* bi = (const float*)d_in[4];
    const float* Wf = (const float*)d_in[5];
    const float* Uf = (const float*)d_in[6];
    const float* bf = (const float*)d_in[7];
    const float* Wg = (const float*)d_in[8];
    const float* Ug = (const float*)d_in[9];
    const float* bg = (const float*)d_in[10];
    const float* Wc = (const float*)d_in[11];
    const float* Uc = (const float*)d_in[12];
    const float* bc = (const float*)d_in[13];
    float* out = (float*)d_out;

    const size_t need = (AB_ELEMS + 4 * PPLANE) * 2;   // ~37.5 MiB
    if (ws_size >= need) {
        unsigned short* Ab = (unsigned short*)d_ws;
        unsigned short* P  = Ab + AB_ELEMS;
        prep_act<<<1024, 256, 0, stream>>>(inputs, states, Ab);
        gemm_fused<<<dim3(64, 4, 4), 256, 0, stream>>>(Wi, Ui, Wf, Uf,
                                                       Wg, Ug, Wc, Uc, Ab, P);
        combine_kernel<<<BH / (8 * 256), 256, 0, stream>>>(out, P, states,
                                                           bi, bf, bg, bc, 4);
    } else {
        unsigned short* P = (unsigned short*)d_ws;
        const int nz = (ws_size >= 4 * PLANE_BYTES) ? 4 : 2;
        const int KB = 4096 / nz;
        dim3 grid(64, 4, nz);
        gemm_tile<<<grid, 256, 0, stream>>>(inputs, states, Wi, Ui, Wf, Uf,
                                            Wg, Ug, Wc, Uc, P, KB);
        combine_kernel<<<BH / (8 * 256), 256, 0, stream>>>(out, P, states,
                                                           bi, bf, bg, bc, nz);
    }
}

// Round 4
// 238.199 us; speedup vs baseline: 1.0640x; 1.0640x over previous
//
#include <hip/hip_runtime.h>

#define BH (512*2048)
#define BHA 1048576ull                   // 512*2048 elems (one activation plane)
#define PPLANE (512ull*8192ull)          // elems per partial plane [512][8192]
#define PLANE_BYTES (PPLANE*2ull)        // bf16
#define AB_ELEMS (2ull*512*2048)         // bf16 activations (inputs + prevstate)

typedef __attribute__((ext_vector_type(8))) short short8;
typedef __attribute__((ext_vector_type(4))) float floatx4;
typedef __attribute__((ext_vector_type(4))) unsigned int uint4v;
typedef __attribute__((ext_vector_type(8))) unsigned short ushort8v;

// pack two f32 -> two bf16 (round-half-up) in one dword (verified R2-R4)
__device__ inline unsigned pk2(float a, float b){
    unsigned ua = __builtin_bit_cast(unsigned, a) + 0x8000u;
    unsigned ub = __builtin_bit_cast(unsigned, b) + 0x8000u;
    return __builtin_amdgcn_perm(ub, ua, 0x07060302u);
}
__device__ inline unsigned short f2bf1(float x){
    return (unsigned short)((__builtin_bit_cast(unsigned, x) + 0x8000u) >> 16);
}
__device__ inline float bf2f(unsigned short s){
    return __builtin_bit_cast(float, ((unsigned)s) << 16);
}
__device__ inline int swz(int r, int g){ return r*4 + (g ^ ((r>>1)&3)); }
__device__ inline float fsig(float x){ return __builtin_amdgcn_rcpf(1.f + __expf(-x)); }
__device__ inline float ftanh(float x){ return 2.f*fsig(2.f*x) - 1.f; }

// ---------------------------------------------------------------------------
// Activation cast only. Casts inputs (plane 0) and states[0] (plane 1) to
// bf16 flat. 1024 blocks.
// ---------------------------------------------------------------------------
__global__ __launch_bounds__(256) void prep_act(
    const float* __restrict__ inputs, const float* __restrict__ states,
    unsigned short* __restrict__ Ab)
{
    const size_t off = ((size_t)blockIdx.x * 256 + threadIdx.x) * 8;
    const float* src = (off < BHA) ? (inputs + off) : (states + (off - BHA));
    floatx4 v0 = *(const floatx4*)src;
    floatx4 v1 = *(const floatx4*)(src + 4);
    uint4v w;
    w.x = pk2(v0[0],v0[1]); w.y = pk2(v0[2],v0[3]);
    w.z = pk2(v1[0],v1[1]); w.w = pk2(v1[2],v1[3]);
    *(uint4v*)(Ab + off) = w;
}

// ---------------------------------------------------------------------------
// Fused GEMM R4: raw s_barrier (NO vmcnt drain) + compiler-counted vmcnt,
// symmetric 2-deep register pipeline on both A and B paths.
// Block 128x128, 4 waves of 64x64 (4x4 x mfma_16x16x32_bf16), BK=32,
// grid (64 n-panels, 4 m-blocks, 4 K-chunks).
// Tile T: loaded to reg set T&1 at iter T-2; ds_written to LDS buf T&1 at
// iter T-1 (regs one full iteration old -> vmcnt(18), never 0); consumed
// by MFMA at iter T. Barrier = lgkmcnt(0) + s_barrier + sched_barrier(0):
// ds_writes visible, global loads stay in flight.
// LDS layout: [row][granule ^ ((row>>1)&3)] XOR swizzle (verified R2/R3,
// SQ_LDS_BANK_CONFLICT = 0).
// ---------------------------------------------------------------------------
__global__ __launch_bounds__(256, 3) void gemm_fused(
    const float* __restrict__ Wi, const float* __restrict__ Ui,
    const float* __restrict__ Wf, const float* __restrict__ Uf,
    const float* __restrict__ Wg, const float* __restrict__ Ug,
    const float* __restrict__ Wc, const float* __restrict__ Uc,
    const unsigned short* __restrict__ Ab, unsigned short* __restrict__ P)
{
    __shared__ unsigned short As[2][4096];   // [m 0..127][k-granule swizzled]
    __shared__ unsigned short Bs[2][4096];   // [n 0..127][k-granule swizzled]

    const int t = threadIdx.x, lane = t & 63, wave = t >> 6;
    const int nblk = blockIdx.x, gate = nblk >> 4, nb = nblk & 15;
    const int m0 = blockIdx.y * 128, z = blockIdx.z;

    // ---- B (weight) staging setup ----
    const float* Bsel;
    if (z < 2) { switch (gate){ case 0: Bsel=Wi; break; case 1: Bsel=Wf; break;
                                case 2: Bsel=Wg; break; default: Bsel=Wc; } }
    else       { switch (gate){ case 0: Bsel=Ui; break; case 1: Bsel=Uf; break;
                                case 2: Bsel=Ug; break; default: Bsel=Uc; } }
    const int n   = t & 127;             // owned B column within panel
    const int o0  = t >> 7;              // first k-octet (0/1); second = o0+2
    const int swkB = (n >> 1) & 3;       // granule swizzle key for row n
    const float* Bp0 = Bsel + ((size_t)((z & 1) * 1024 + o0 * 8)) * 2048
                            + nb * 128 + n;
    const float* Bp1 = Bp0 + (size_t)16 * 2048;   // octet o0+2
    // B LDS write offsets (shorts): phys granule = octet ^ swkB
    const int wb0 = n * 32 + (((o0    ) ^ swkB) << 3);
    const int wb1 = n * 32 + (((o0 + 2) ^ swkB) << 3);

    // ---- A staging setup (register-staged from bf16 Ab) ----
    // thread t: row r = t>>1 (0..127), half h = t&1 -> granules 2h, 2h+1
    const int ar = t >> 1, ah = t & 1;
    const int swkA = (ar >> 1) & 3;
    const unsigned short* Aptr = Ab + (size_t)(z >> 1) * BHA
                               + (size_t)(m0 + ar) * 2048 + (z & 1) * 1024
                               + ah * 16;
    const int wa0 = ar * 32 + (((2*ah    ) ^ swkA) << 3);
    const int wa1 = ar * 32 + (((2*ah + 1) ^ swkA) << 3);

    floatx4 acc[4][4];
    #pragma unroll
    for (int i = 0; i < 4; i++)
        #pragma unroll
        for (int j = 0; j < 4; j++)
            acc[i][j] = (floatx4){0.f,0.f,0.f,0.f};

    const int wm = (wave & 1) * 64, wn = (wave >> 1) * 64;
    const int row16 = lane & 15, g4 = lane >> 4;
    const int fgx = ((g4 ^ ((row16 >> 1) & 3)) << 3);  // swizzled frag granule

    float uB0a[8], uB0b[8], uB1a[8], uB1b[8];   // B reg sets 0/1
    uint4v uA0a, uA0b, uA1a, uA1b;              // A reg sets 0/1

#define B_LOAD(d0, d1, tile) do { \
    const float* q0_ = Bp0 + (size_t)(tile) * 65536; \
    const float* q1_ = Bp1 + (size_t)(tile) * 65536; \
    _Pragma("unroll") for (int j = 0; j < 8; j++) d0[j] = q0_[(size_t)j * 2048]; \
    _Pragma("unroll") for (int j = 0; j < 8; j++) d1[j] = q1_[(size_t)j * 2048]; \
} while(0)

#define B_WRITE(buf, s0, s1) do { \
    *(uint4v*)&Bs[buf][wb0] = (uint4v){pk2(s0[0],s0[1]), pk2(s0[2],s0[3]), \
                                       pk2(s0[4],s0[5]), pk2(s0[6],s0[7])}; \
    *(uint4v*)&Bs[buf][wb1] = (uint4v){pk2(s1[0],s1[1]), pk2(s1[2],s1[3]), \
                                       pk2(s1[4],s1[5]), pk2(s1[6],s1[7])}; \
} while(0)

#define A_LOAD(da, db, tile) do { \
    const unsigned short* ap_ = Aptr + (size_t)(tile) * 32; \
    da = *(const uint4v*)ap_; db = *(const uint4v*)(ap_ + 8); \
} while(0)

#define A_WRITE(buf, sa, sb) do { \
    *(uint4v*)&As[buf][wa0] = sa; *(uint4v*)&As[buf][wa1] = sb; \
} while(0)

#define FRAGS_MFMA(buf) do { \
    short8 afr[4], bfr[4]; \
    _Pragma("unroll") for (int mi = 0; mi < 4; mi++) \
        afr[mi] = *(const short8*)&As[buf][(wm + mi*16 + row16)*32 + fgx]; \
    _Pragma("unroll") for (int ni = 0; ni < 4; ni++) \
        bfr[ni] = *(const short8*)&Bs[buf][(wn + ni*16 + row16)*32 + fgx]; \
    _Pragma("unroll") for (int mi = 0; mi < 4; mi++) \
        _Pragma("unroll") for (int ni = 0; ni < 4; ni++) \
            acc[mi][ni] = __builtin_amdgcn_mfma_f32_16x16x32_bf16( \
                afr[mi], bfr[ni], acc[mi][ni], 0, 0, 0); \
} while(0)

// ds_writes visible to the group WITHOUT draining global loads:
// lgkmcnt(0) (LDS ops done) + raw s_barrier + hard scheduler fence so
// next-phase ds_reads cannot hoist above the barrier.
#define PIPE_BARRIER() do { \
    asm volatile("s_waitcnt lgkmcnt(0)" ::: "memory"); \
    __builtin_amdgcn_s_barrier(); \
    __builtin_amdgcn_sched_barrier(0); \
} while(0)

    // ---- prologue: tiles 0,1 -> reg sets 0,1; tile 0 -> LDS buf 0 ----
    A_LOAD(uA0a, uA0b, 0); B_LOAD(uB0a, uB0b, 0);
    A_LOAD(uA1a, uA1b, 1); B_LOAD(uB1a, uB1b, 1);
    A_WRITE(0, uA0a, uA0b);
    B_WRITE(0, uB0a, uB0b);
    PIPE_BARRIER();

    for (int kk = 0; kk < 32; kk += 2) {
        // even iter kk: load tile kk+2 -> set0; compute buf0; write tile kk+1
        if (kk < 30) { A_LOAD(uA0a, uA0b, kk + 2); B_LOAD(uB0a, uB0b, kk + 2); }
        FRAGS_MFMA(0);
        A_WRITE(1, uA1a, uA1b);
        B_WRITE(1, uB1a, uB1b);
        PIPE_BARRIER();
        // odd iter kk+1: load tile kk+3 -> set1; compute buf1; write tile kk+2
        if (kk < 30) { A_LOAD(uA1a, uA1b, kk + 3); B_LOAD(uB1a, uB1b, kk + 3); }
        FRAGS_MFMA(1);
        if (kk < 30) {
            A_WRITE(0, uA0a, uA0b);
            B_WRITE(0, uB0a, uB0b);
        }
        PIPE_BARRIER();
    }

#undef B_LOAD
#undef B_WRITE
#undef A_LOAD
#undef A_WRITE
#undef FRAGS_MFMA
#undef PIPE_BARRIER

    unsigned short* dst = P + (size_t)z * PPLANE;
    const int gbase = gate * 2048 + nb * 128;
    #pragma unroll
    for (int mi = 0; mi < 4; mi++)
        #pragma unroll
        for (int ni = 0; ni < 4; ni++)
            #pragma unroll
            for (int j = 0; j < 4; j++) {
                int row = m0 + wm + mi*16 + g4*4 + j;
                int col = gbase + wn + ni*16 + row16;
                dst[(size_t)row * 8192 + col] = f2bf1(acc[mi][ni][j]);
            }
}

// ---------------------------------------------------------------------------
// Fallback GEMM (fused fp32 staging) for small ws_size.
// ---------------------------------------------------------------------------
__global__ __launch_bounds__(256, 2) void gemm_tile(
    const float* __restrict__ inputs, const float* __restrict__ states,
    const float* __restrict__ Wi, const float* __restrict__ Ui,
    const float* __restrict__ Wf, const float* __restrict__ Uf,
    const float* __restrict__ Wg, const float* __restrict__ Ug,
    const float* __restrict__ Wc, const float* __restrict__ Uc,
    unsigned short* __restrict__ P, int KB)
{
    __shared__ uint4v As[2][512];
    __shared__ uint4v Bs[2][512];

    const int t = threadIdx.x;
    const int m0 = blockIdx.y * 128;
    const int z = blockIdx.z;
    const int nblk = blockIdx.x;
    const int gate = nblk >> 4;
    const int c0 = (nblk & 15) * 128;
    const int gk = z * KB;

    const float* Abase; const float* Bsel; int ko;
    if (gk < 2048) {
        Abase = inputs; ko = gk;
        switch (gate){ case 0: Bsel=Wi; break; case 1: Bsel=Wf; break;
                       case 2: Bsel=Wg; break; default: Bsel=Wc; }
    } else {
        Abase = states; ko = gk - 2048;
        switch (gate){ case 0: Bsel=Ui; break; case 1: Bsel=Uf; break;
                       case 2: Bsel=Ug; break; default: Bsel=Uc; }
    }
    const int NIT = KB >> 5;

    const int lane = t & 63, wave = t >> 6;
    const int wm = (wave & 1) * 64, wn = (wave >> 1) * 64;
    const int row16 = lane & 15, g4 = lane >> 4;
    const int ar = t >> 2, ag = t & 3;
    const int bn = t & 127, bg2 = (t >> 7) * 2;

    const float* Ap = Abase + (size_t)(m0 + ar) * 2048 + ko + ag * 8;
    const float* Bp = Bsel + (size_t)ko * 2048 + c0 + bn;

    floatx4 acc[4][4];
    #pragma unroll
    for (int i = 0; i < 4; i++)
        #pragma unroll
        for (int j = 0; j < 4; j++)
            acc[i][j] = (floatx4){0.f,0.f,0.f,0.f};

    floatx4 a0,a1,a2,a3; float b0[8], b1[8];
    a0 = *(const floatx4*)Ap;             a1 = *(const floatx4*)(Ap + 4);
    a2 = *(const floatx4*)(Ap + 64*2048); a3 = *(const floatx4*)(Ap + 64*2048 + 4);
    #pragma unroll
    for (int j = 0; j < 8; j++) b0[j] = Bp[(size_t)(bg2*8 + j) * 2048];
    #pragma unroll
    for (int j = 0; j < 8; j++) b1[j] = Bp[(size_t)(bg2*8 + 8 + j) * 2048];
    {
        uint4v w;
        w.x=pk2(a0[0],a0[1]); w.y=pk2(a0[2],a0[3]); w.z=pk2(a1[0],a1[1]); w.w=pk2(a1[2],a1[3]);
        As[0][swz(ar, ag)] = w;
        w.x=pk2(a2[0],a2[1]); w.y=pk2(a2[2],a2[3]); w.z=pk2(a3[0],a3[1]); w.w=pk2(a3[2],a3[3]);
        As[0][swz(ar+64, ag)] = w;
        w.x=pk2(b0[0],b0[1]); w.y=pk2(b0[2],b0[3]); w.z=pk2(b0[4],b0[5]); w.w=pk2(b0[6],b0[7]);
        Bs[0][swz(bn, bg2)] = w;
        w.x=pk2(b1[0],b1[1]); w.y=pk2(b1[2],b1[3]); w.z=pk2(b1[4],b1[5]); w.w=pk2(b1[6],b1[7]);
        Bs[0][swz(bn, bg2+1)] = w;
    }

    for (int kk = 0; kk < NIT; kk++) {
        __syncthreads();
        const int cur = kk & 1;
        if (kk + 1 < NIT) {
            const float* ap = Ap + (kk+1) * 32;
            a0 = *(const floatx4*)ap;             a1 = *(const floatx4*)(ap + 4);
            a2 = *(const floatx4*)(ap + 64*2048); a3 = *(const floatx4*)(ap + 64*2048 + 4);
            const float* bp = Bp + (size_t)(kk+1) * 32 * 2048;
            #pragma unroll
            for (int j = 0; j < 8; j++) b0[j] = bp[(size_t)(bg2*8 + j) * 2048];
            #pragma unroll
            for (int j = 0; j < 8; j++) b1[j] = bp[(size_t)(bg2*8 + 8 + j) * 2048];
        }
        short8 afr[4], bfr[4];
        #pragma unroll
        for (int mi = 0; mi < 4; mi++)
            afr[mi] = *(const short8*)&As[cur][swz(wm + mi*16 + row16, g4)];
        #pragma unroll
        for (int ni = 0; ni < 4; ni++)
            bfr[ni] = *(const short8*)&Bs[cur][swz(wn + ni*16 + row16, g4)];
        #pragma unroll
        for (int mi = 0; mi < 4; mi++)
            #pragma unroll
            for (int ni = 0; ni < 4; ni++)
                acc[mi][ni] = __builtin_amdgcn_mfma_f32_16x16x32_bf16(
                    afr[mi], bfr[ni], acc[mi][ni], 0, 0, 0);
        if (kk + 1 < NIT) {
            const int nxt = cur ^ 1;
            uint4v w;
            w.x=pk2(a0[0],a0[1]); w.y=pk2(a0[2],a0[3]); w.z=pk2(a1[0],a1[1]); w.w=pk2(a1[2],a1[3]);
            As[nxt][swz(ar, ag)] = w;
            w.x=pk2(a2[0],a2[1]); w.y=pk2(a2[2],a2[3]); w.z=pk2(a3[0],a3[1]); w.w=pk2(a3[2],a3[3]);
            As[nxt][swz(ar+64, ag)] = w;
            w.x=pk2(b0[0],b0[1]); w.y=pk2(b0[2],b0[3]); w.z=pk2(b0[4],b0[5]); w.w=pk2(b0[6],b0[7]);
            Bs[nxt][swz(bn, bg2)] = w;
            w.x=pk2(b1[0],b1[1]); w.y=pk2(b1[2],b1[3]); w.z=pk2(b1[4],b1[5]); w.w=pk2(b1[6],b1[7]);
            Bs[nxt][swz(bn, bg2+1)] = w;
        }
    }

    unsigned short* dst = P + (size_t)z * PPLANE;
    const int gbase = gate * 2048 + c0;
    #pragma unroll
    for (int mi = 0; mi < 4; mi++)
        #pragma unroll
        for (int ni = 0; ni < 4; ni++)
            #pragma unroll
            for (int j = 0; j < 4; j++) {
                int row = m0 + wm + mi*16 + g4*4 + j;
                int col = gbase + wn + ni*16 + row16;
                dst[(size_t)row * 8192 + col] = f2bf1(acc[mi][ni][j]);
            }
}

// activations + LSTM combine
__global__ __launch_bounds__(256) void combine_kernel(
    float* __restrict__ out, const unsigned short* __restrict__ P,
    const float* __restrict__ states,
    const float* __restrict__ bi, const float* __restrict__ bfv,
    const float* __restrict__ bg, const float* __restrict__ bc, int nz)
{
    const int idx = (blockIdx.x * 256 + threadIdx.x) * 8;
    const int row = idx >> 11;
    const int h = idx & 2047;
    const size_t base = (size_t)row * 8192 + h;

    float xi[8], xf[8], xg[8], xc[8];
    #pragma unroll
    for (int e = 0; e < 8; e++) {
        xi[e] = bi[h+e]; xf[e] = bfv[h+e]; xg[e] = bg[h+e]; xc[e] = bc[h+e];
    }
    for (int z = 0; z < nz; z++) {
        const unsigned short* Pz = P + (size_t)z * PPLANE;
        ushort8v vi = *(const ushort8v*)&Pz[base];
        ushort8v vf = *(const ushort8v*)&Pz[base + 2048];
        ushort8v vg = *(const ushort8v*)&Pz[base + 4096];
        ushort8v vc = *(const ushort8v*)&Pz[base + 6144];
        #pragma unroll
        for (int e = 0; e < 8; e++) {
            xi[e] += bf2f(vi[e]); xf[e] += bf2f(vf[e]);
            xg[e] += bf2f(vg[e]); xc[e] += bf2f(vc[e]);
        }
    }

    const float* po = states + BH;
    floatx4 pov[2];
    pov[0] = *(const floatx4*)&po[idx];
    pov[1] = *(const floatx4*)&po[idx + 4];

    floatx4 vcv[2], vsv[2];
    #pragma unroll
    for (int q = 0; q < 2; q++)
        #pragma unroll
        for (int j = 0; j < 4; j++) {
            int e = q*4 + j;
            float c = fsig(xf[e]) * pov[q][j] + fsig(xi[e]) * ftanh(xc[e]);
            vcv[q][j] = c;
            vsv[q][j] = fsig(xg[e]) * ftanh(c);
        }
    #pragma unroll
    for (int q = 0; q < 2; q++) {
        *(floatx4*)&out[idx + q*4]        = vcv[q];
        *(floatx4*)&out[BH + idx + q*4]   = vsv[q];
        *(floatx4*)&out[2*BH + idx + q*4] = vcv[q];
    }
}

extern "C" void kernel_launch(void* const* d_in, const int* in_sizes, int n_in,
                              void* d_out, int out_size, void* d_ws, size_t ws_size,
                              hipStream_t stream) {
    const float* inputs = (const float*)d_in[0];
    const float* states = (const float*)d_in[1];
    const float* Wi = (const float*)d_in[2];
    const float* Ui = (const float*)d_in[3];
    const float* bi = (const float*)d_in[4];
    const float* Wf = (const float*)d_in[5];
    const float* Uf = (const float*)d_in[6];
    const float* bf = (const float*)d_in[7];
    const float* Wg = (const float*)d_in[8];
    const float* Ug = (const float*)d_in[9];
    const float* bg = (const float*)d_in[10];
    const float* Wc = (const float*)d_in[11];
    const float* Uc = (const float*)d_in[12];
    const float* bc = (const float*)d_in[13];
    float* out = (float*)d_out;

    const size_t need = (AB_ELEMS + 4 * PPLANE) * 2;   // ~37.5 MiB
    if (ws_size >= need) {
        unsigned short* Ab = (unsigned short*)d_ws;
        unsigned short* P  = Ab + AB_ELEMS;
        prep_act<<<1024, 256, 0, stream>>>(inputs, states, Ab);
        gemm_fused<<<dim3(64, 4, 4), 256, 0, stream>>>(Wi, Ui, Wf, Uf,
                                                       Wg, Ug, Wc, Uc, Ab, P);
        combine_kernel<<<BH / (8 * 256), 256, 0, stream>>>(out, P, states,
                                                           bi, bf, bg, bc, 4);
    } else {
        unsigned short* P = (unsigned short*)d_ws;
        const int nz = (ws_size >= 4 * PLANE_BYTES) ? 4 : 2;
        const int KB = 4096 / nz;
        dim3 grid(64, 4, nz);
        gemm_tile<<<grid, 256, 0, stream>>>(inputs, states, Wi, Ui, Wf, Uf,
                                            Wg, Ug, Wc, Uc, P, KB);
        combine_kernel<<<BH / (8 * 256), 256, 0, stream>>>(out, P, states,
                                                           bi, bf, bg, bc, nz);
    }
}